// Round 2
// baseline (550.579 us; speedup 1.0000x reference)
//
#include <hip/hip_runtime.h>
#include <hip/hip_bf16.h>

typedef __bf16 bf16;
typedef __bf16 bf16x8 __attribute__((ext_vector_type(8)));
typedef float  f32x4  __attribute__((ext_vector_type(4)));

// async 16B global->LDS copy. LDS dest must be wave-uniform base; HW adds lane*16.
__device__ __forceinline__ void async16(const bf16* g, bf16* l) {
  __builtin_amdgcn_global_load_lds(
      (__attribute__((address_space(1))) void*)g,
      (__attribute__((address_space(3))) void*)l,
      16, 0, 0);
}

// C = act(alpha * (A @ W^T) + bias)   A:[M,K] bf16 row-major, W:[N,K] bf16 row-major
// EPI=0: store OT to C (ldc stride).  ACT: 0 none, 1 tanh, 2 relu
// EPI=1: score epilogue: ws[row] += sum_col tanh(acc) * y[row>>4, col]  (atomic fp32)
// Tiles: 128x128, BK=64, 256 threads = 4 waves, each wave 64x64 via 4x4 of 16x16x32 MFMA.
template<int EPI, int ACT, typename OT>
__global__ __launch_bounds__(256, 2)
void gemm_bt(const bf16* __restrict__ A, const bf16* __restrict__ W,
             OT* __restrict__ C, int K, int ldc, float alpha,
             const float* __restrict__ bias,
             const bf16* __restrict__ y, float* __restrict__ ws) {
  __shared__ bf16 As[128 * 64];
  __shared__ bf16 Bs[128 * 64];
  const int tid  = threadIdx.x;
  const int wave = tid >> 6, lane = tid & 63;
  const int wr = wave >> 1, wc = wave & 1;
  const int g = lane >> 4, l4 = lane & 15;

  f32x4 acc[4][4];
#pragma unroll
  for (int i = 0; i < 4; ++i)
#pragma unroll
    for (int j = 0; j < 4; ++j)
      acc[i][j] = (f32x4){0.f, 0.f, 0.f, 0.f};

  const bf16* Abase = A + (size_t)blockIdx.x * 128 * K;
  const bf16* Wbase = W + (size_t)blockIdx.y * 128 * K;

  for (int k0 = 0; k0 < K; k0 += 64) {
#pragma unroll
    for (int i = 0; i < 4; ++i) {
      const int cb  = i * 256 + wave * 64;   // wave-uniform chunk base
      const int c   = cb + lane;             // per-lane chunk (1024 chunks of 16B per tile)
      const int row = c >> 3;
      const int kk  = (c & 7) << 3;
      async16(Abase + (size_t)row * K + k0 + kk, &As[cb * 8]);
      async16(Wbase + (size_t)row * K + k0 + kk, &Bs[cb * 8]);
    }
    __syncthreads();
#pragma unroll
    for (int s = 0; s < 2; ++s) {
      const int koff = s * 32 + g * 8;
      bf16x8 af[4], bfr[4];
#pragma unroll
      for (int i = 0; i < 4; ++i)
        af[i] = *(const bf16x8*)&As[(wr * 64 + i * 16 + l4) * 64 + koff];
#pragma unroll
      for (int j = 0; j < 4; ++j)
        bfr[j] = *(const bf16x8*)&Bs[(wc * 64 + j * 16 + l4) * 64 + koff];
#pragma unroll
      for (int i = 0; i < 4; ++i)
#pragma unroll
        for (int j = 0; j < 4; ++j)
          acc[i][j] = __builtin_amdgcn_mfma_f32_16x16x32_bf16(af[i], bfr[j], acc[i][j], 0, 0, 0);
    }
    __syncthreads();
  }

  const int rbase = blockIdx.x * 128 + wr * 64;
  const int cbase = blockIdx.y * 128 + wc * 64;

  if (EPI == 0) {
#pragma unroll
    for (int i = 0; i < 4; ++i)
#pragma unroll
      for (int j = 0; j < 4; ++j) {
        const int col = cbase + j * 16 + l4;
        const float bv = bias ? bias[col] : 0.f;
#pragma unroll
        for (int r = 0; r < 4; ++r) {
          const int row = rbase + i * 16 + g * 4 + r;
          float v = acc[i][j][r] * alpha + bv;
          if (ACT == 1) v = tanhf(v);
          if (ACT == 2) v = fmaxf(v, 0.f);
          C[(size_t)row * ldc + col] = (OT)v;
        }
      }
  } else {
    // rows of a 16-row tile all belong to one node (K=16 neighbors, tiles 16-aligned)
#pragma unroll
    for (int i = 0; i < 4; ++i) {
      const int arow0 = rbase + i * 16;
      const int node  = arow0 >> 4;
      float p0 = 0.f, p1 = 0.f, p2 = 0.f, p3 = 0.f;
#pragma unroll
      for (int j = 0; j < 4; ++j) {
        const float yv = (float)y[(size_t)node * 512 + cbase + j * 16 + l4];
        p0 += tanhf(acc[i][j][0]) * yv;
        p1 += tanhf(acc[i][j][1]) * yv;
        p2 += tanhf(acc[i][j][2]) * yv;
        p3 += tanhf(acc[i][j][3]) * yv;
      }
#pragma unroll
      for (int m = 1; m < 16; m <<= 1) {  // reduce over the 16 cols held by this lane group
        p0 += __shfl_xor(p0, m);
        p1 += __shfl_xor(p1, m);
        p2 += __shfl_xor(p2, m);
        p3 += __shfl_xor(p3, m);
      }
      if (l4 == 0) {
        atomicAdd(&ws[arow0 + g * 4 + 0], p0);
        atomicAdd(&ws[arow0 + g * 4 + 1], p1);
        atomicAdd(&ws[arow0 + g * 4 + 2], p2);
        atomicAdd(&ws[arow0 + g * 4 + 3], p3);
      }
    }
  }
}

// big f32->bf16 conversions: x (1024 blocks), neibs (16384), edge (8192); 2048 elems/block
__global__ void cvt_big(const float* __restrict__ s0, bf16* __restrict__ d0,
                        const float* __restrict__ s1, bf16* __restrict__ d1,
                        const float* __restrict__ s2, bf16* __restrict__ d2) {
  const int b = blockIdx.x;
  const float* s; bf16* d; size_t base;
  if (b < 1024)       { s = s0; d = d0; base = (size_t)b * 2048; }
  else if (b < 17408) { s = s1; d = d1; base = (size_t)(b - 1024) * 2048; }
  else                { s = s2; d = d2; base = (size_t)(b - 17408) * 2048; }
  const size_t i = base + (size_t)threadIdx.x * 8;
  const float4 a = *(const float4*)(s + i);
  const float4 c = *(const float4*)(s + i + 4);
  bf16x8 o = { (bf16)a.x, (bf16)a.y, (bf16)a.z, (bf16)a.w,
               (bf16)c.x, (bf16)c.y, (bf16)c.z, (bf16)c.w };
  *(bf16x8*)(d + i) = o;
}

struct CvtEnt { const float* s; bf16* d; int n; };
struct CvtArgs { CvtEnt e[7]; };

__global__ void cvt_small(CvtArgs args) {
  const CvtEnt ent = args.e[blockIdx.y];
  const int i = blockIdx.x * 2048 + threadIdx.x * 8;
  if (i < ent.n) {
    const float4 a = *(const float4*)(ent.s + i);
    const float4 c = *(const float4*)(ent.s + i + 4);
    bf16x8 o = { (bf16)a.x, (bf16)a.y, (bf16)a.z, (bf16)a.w,
                 (bf16)c.x, (bf16)c.y, (bf16)c.z, (bf16)c.w };
    *(bf16x8*)(ent.d + i) = o;
  }
}

// fused 512x512 transpose + f32->bf16 (so y = x_att @ W2 can use the same B^T GEMM)
__global__ void transpose512f(const float* __restrict__ s, bf16* __restrict__ d) {
  __shared__ float t[16][17];
  const int x0 = blockIdx.x * 16, y0 = blockIdx.y * 16;
  t[threadIdx.y][threadIdx.x] = s[(size_t)(y0 + threadIdx.y) * 512 + x0 + threadIdx.x];
  __syncthreads();
  d[(size_t)(x0 + threadIdx.y) * 512 + (y0 + threadIdx.x)] = (bf16)t[threadIdx.x][threadIdx.y];
}

// per node: softmax over K=16 raw scores (edge scores masked), aggregate neibs/edges
__global__ void softmax_agg(const float* __restrict__ wsn, const float* __restrict__ wse,
                            const int* __restrict__ mask,
                            const bf16* __restrict__ neibs, const bf16* __restrict__ edge,
                            bf16* __restrict__ aggn, bf16* __restrict__ agge) {
  const int n = blockIdx.x;
  const int t = threadIdx.x;
  __shared__ float wn[16], we[16];
  if (t < 16) {
    wn[t] = wsn[n * 16 + t];
    we[t] = wse[n * 16 + t] - 9999999.0f * (float)mask[n * 16 + t];
  }
  __syncthreads();
  if (t == 0) {
    float m = wn[0];
    for (int k = 1; k < 16; ++k) m = fmaxf(m, wn[k]);
    float s = 0.f;
    for (int k = 0; k < 16; ++k) { wn[k] = expf(wn[k] - m); s += wn[k]; }
    s = 1.f / s;
    for (int k = 0; k < 16; ++k) wn[k] *= s;
  } else if (t == 64) {
    float m = we[0];
    for (int k = 1; k < 16; ++k) m = fmaxf(m, we[k]);
    float s = 0.f;
    for (int k = 0; k < 16; ++k) { we[k] = expf(we[k] - m); s += we[k]; }
    s = 1.f / s;
    for (int k = 0; k < 16; ++k) we[k] *= s;
  }
  __syncthreads();
  {
    const bf16* nb = neibs + (size_t)n * 16 * 256 + t;
    float a = 0.f;
#pragma unroll
    for (int k = 0; k < 16; ++k) a += wn[k] * (float)nb[(size_t)k * 256];
    aggn[(size_t)n * 256 + t] = (bf16)a;
  }
  if (t < 128) {
    const bf16* eb = edge + (size_t)n * 16 * 128 + t;
    float a = 0.f;
#pragma unroll
    for (int k = 0; k < 16; ++k) a += we[k] * (float)eb[(size_t)k * 128];
    agge[(size_t)n * 128 + t] = (bf16)a;
  }
}

extern "C" void kernel_launch(void* const* d_in, const int* in_sizes, int n_in,
                              void* d_out, int out_size, void* d_ws, size_t ws_size,
                              hipStream_t stream) {
  const float* x     = (const float*)d_in[0];
  const float* neibs = (const float*)d_in[1];
  const float* edge  = (const float*)d_in[2];
  const int*   mask  = (const int*)d_in[3];
  const float* W1x = (const float*)d_in[4];
  const float* W2x = (const float*)d_in[5];
  const float* W1n = (const float*)d_in[6];
  const float* W2n = (const float*)d_in[7];
  const float* W1e = (const float*)d_in[8];
  const float* W2e = (const float*)d_in[9];
  const float* Wfx = (const float*)d_in[10];
  const float* bfx = (const float*)d_in[11];
  const float* Wfn = (const float*)d_in[12];
  const float* bfn = (const float*)d_in[13];
  const float* Wfe = (const float*)d_in[14];
  const float* bfe = (const float*)d_in[15];
  float* out = (float*)d_out;

  char* wsb = (char*)d_ws;
  const size_t MB = 1024 * 1024;
  float* ws_n  = (float*)(wsb + 0);                // 512KB (131072 fp32)
  float* ws_e  = (float*)(wsb + 512 * 1024);       // 512KB (adjacent -> one memset)
  bf16* W2nT   = (bf16*)(wsb + 1 * MB);            // 512KB
  bf16* W2eT   = (bf16*)(wsb + 1 * MB + 512 * 1024);
  bf16* h_x    = (bf16*)(wsb + 2 * MB);            // 8MB  (reused as y_e later)
  bf16* x_att  = (bf16*)(wsb + 10 * MB);           // 8MB  (reused as aggn later)
  bf16* agge   = (bf16*)(wsb + 14 * MB);           // 2MB  (upper half of dead x_att)
  bf16* y_n    = (bf16*)(wsb + 18 * MB);           // 8MB
  bf16* xb     = (bf16*)(wsb + 26 * MB);           // 4MB
  bf16* nb     = (bf16*)(wsb + 30 * MB);           // 64MB
  bf16* eb     = (bf16*)(wsb + 94 * MB);           // 32MB
  char* wtb    = wsb + 126 * MB;                   // bf16 weights, 1.44MB
  bf16* W1xb = (bf16*)(wtb + 0);
  bf16* W2xb = (bf16*)(wtb + 256 * 1024);
  bf16* W1nb = (bf16*)(wtb + 768 * 1024);
  bf16* W1eb = (bf16*)(wtb + 1024 * 1024);
  bf16* Wfxb = (bf16*)(wtb + 1152 * 1024);
  bf16* Wfnb = (bf16*)(wtb + 1280 * 1024);
  bf16* Wfeb = (bf16*)(wtb + 1408 * 1024);
  bf16* y_e  = h_x;                                // h_x dead after x_att GEMM
  bf16* aggn = x_att;                              // x_att dead after y_e GEMM

  const float inv_sqrt512 = 0.04419417382415922f;

  hipMemsetAsync(ws_n, 0, 1 * MB, stream);  // zero ws_n + ws_e for atomics

  cvt_big<<<25600, 256, 0, stream>>>(x, xb, neibs, nb, edge, eb);

  CvtArgs ca;
  ca.e[0] = {W1x, W1xb, 131072};
  ca.e[1] = {W2x, W2xb, 262144};
  ca.e[2] = {W1n, W1nb, 131072};
  ca.e[3] = {W1e, W1eb, 65536};
  ca.e[4] = {Wfx, Wfxb, 65536};
  ca.e[5] = {Wfn, Wfnb, 65536};
  ca.e[6] = {Wfe, Wfeb, 32768};
  cvt_small<<<dim3(128, 7), 256, 0, stream>>>(ca);

  transpose512f<<<dim3(32, 32), dim3(16, 16), 0, stream>>>(W2n, W2nT);
  transpose512f<<<dim3(32, 32), dim3(16, 16), 0, stream>>>(W2e, W2eT);

  // x MLP: h_x = tanh(x @ W1x^T); x_att = h_x @ W2x^T
  gemm_bt<0, 1, bf16><<<dim3(64, 4), 256, 0, stream>>>(xb, W1xb, h_x, 256, 512, 1.f, nullptr, nullptr, nullptr);
  gemm_bt<0, 0, bf16><<<dim3(64, 4), 256, 0, stream>>>(h_x, W2xb, x_att, 512, 512, 1.f, nullptr, nullptr, nullptr);
  // y_n = (x_att @ W2n) / sqrt(512);  y_e = x_att @ W2e
  gemm_bt<0, 0, bf16><<<dim3(64, 4), 256, 0, stream>>>(x_att, W2nT, y_n, 512, 512, inv_sqrt512, nullptr, nullptr, nullptr);
  gemm_bt<0, 0, bf16><<<dim3(64, 4), 256, 0, stream>>>(x_att, W2eT, y_e, 512, 512, 1.f, nullptr, nullptr, nullptr);

  // fused scores: ws_n[r] = tanh(neibs[r] @ W1n^T) . y_n[r>>4]  (and edge analog)
  gemm_bt<1, 0, bf16><<<dim3(1024, 4), 256, 0, stream>>>(nb, W1nb, nullptr, 256, 0, 1.f, nullptr, y_n, ws_n);
  gemm_bt<1, 0, bf16><<<dim3(1024, 4), 256, 0, stream>>>(eb, W1eb, nullptr, 128, 0, 1.f, nullptr, y_e, ws_e);

  softmax_agg<<<8192, 256, 0, stream>>>(ws_n, ws_e, mask, nb, eb, aggn, agge);

  // out = relu([x@Wfx^T+bfx | aggn@Wfn^T+bfn | agge@Wfe^T+bfe]), row stride 768, f32 out
  gemm_bt<0, 2, float><<<dim3(64, 2), 256, 0, stream>>>(xb,   Wfxb, out + 0,   256, 768, 1.f, bfx, nullptr, nullptr);
  gemm_bt<0, 2, float><<<dim3(64, 2), 256, 0, stream>>>(aggn, Wfnb, out + 256, 256, 768, 1.f, bfn, nullptr, nullptr);
  gemm_bt<0, 2, float><<<dim3(64, 2), 256, 0, stream>>>(agge, Wfeb, out + 512, 128, 768, 1.f, bfe, nullptr, nullptr);
}

// Round 4
// 480.730 us; speedup vs baseline: 1.1453x; 1.1453x over previous
//
#include <hip/hip_runtime.h>
#include <hip/hip_bf16.h>

typedef __bf16 bf16;
typedef __bf16 bf16x8 __attribute__((ext_vector_type(8)));
typedef float  f32x4  __attribute__((ext_vector_type(4)));

// async 16B global->LDS copy. LDS dest must be wave-uniform base; HW adds lane*16.
__device__ __forceinline__ void async16(const bf16* g, bf16* l) {
  __builtin_amdgcn_global_load_lds(
      (__attribute__((address_space(1))) void*)g,
      (__attribute__((address_space(3))) void*)l,
      16, 0, 0);
}

// Hard fence + barrier: drain ALL outstanding vmem (incl. global_load_lds LDS
// writes) and lds ops BEFORE the barrier, with a full compiler memory fence so
// no staging intrinsic can be scheduled across it (nested-loop CFG safety).
__device__ __forceinline__ void fence_barrier() {
  asm volatile("s_waitcnt vmcnt(0) lgkmcnt(0)" ::: "memory");
  __syncthreads();
}

// tanh(x) = 1 - 2/(exp2(2*log2e*x)+1); v_exp_f32+v_rcp_f32, ~1e-6 abs err
__device__ __forceinline__ float fast_tanh(float x) {
  float e = __builtin_amdgcn_exp2f(x * 2.88539008177793f);
  return 1.f - 2.f * __builtin_amdgcn_rcpf(e + 1.f);
}

// ---------------- 64x64-tile GEMM: C = act(alpha*(A@W^T)+bias) ----------------
// A:[M,K] bf16 rm, W:[N,K] bf16 rm. 256 thr = 4 waves, each 32x32 via 2x2 MFMA.
// ACT: 0 none, 1 tanh, 2 relu.  OT: bf16 or float.
template<int ACT, typename OT>
__global__ __launch_bounds__(256, 4)
void gemm64(const bf16* __restrict__ A, const bf16* __restrict__ W,
            OT* __restrict__ C, int K, int ldc, float alpha,
            const float* __restrict__ bias) {
  __shared__ bf16 As[64 * 64];
  __shared__ bf16 Bs[64 * 64];
  const int tid  = threadIdx.x;
  const int wave = tid >> 6, lane = tid & 63;
  const int wr = wave >> 1, wc = wave & 1;
  const int g = lane >> 4, l4 = lane & 15;

  f32x4 acc[2][2];
#pragma unroll
  for (int i = 0; i < 2; ++i)
#pragma unroll
    for (int j = 0; j < 2; ++j)
      acc[i][j] = (f32x4){0.f, 0.f, 0.f, 0.f};

  const bf16* Abase = A + (size_t)blockIdx.x * 64 * K;
  const bf16* Wbase = W + (size_t)blockIdx.y * 64 * K;

  for (int k0 = 0; k0 < K; k0 += 64) {
#pragma unroll
    for (int i = 0; i < 2; ++i) {          // 512 chunks of 16B per tile
      const int cb  = i * 256 + wave * 64; // wave-uniform
      const int c   = cb + lane;
      const int row = c >> 3;
      const int kk  = (c & 7) << 3;
      async16(Abase + (size_t)row * K + k0 + kk, &As[cb * 8]);
      async16(Wbase + (size_t)row * K + k0 + kk, &Bs[cb * 8]);
    }
    fence_barrier();
#pragma unroll
    for (int s = 0; s < 2; ++s) {
      const int koff = s * 32 + g * 8;
      bf16x8 af[2], bfr[2];
#pragma unroll
      for (int i = 0; i < 2; ++i)
        af[i] = *(const bf16x8*)&As[(wr * 32 + i * 16 + l4) * 64 + koff];
#pragma unroll
      for (int j = 0; j < 2; ++j)
        bfr[j] = *(const bf16x8*)&Bs[(wc * 32 + j * 16 + l4) * 64 + koff];
#pragma unroll
      for (int i = 0; i < 2; ++i)
#pragma unroll
        for (int j = 0; j < 2; ++j)
          acc[i][j] = __builtin_amdgcn_mfma_f32_16x16x32_bf16(af[i], bfr[j], acc[i][j], 0, 0, 0);
    }
    fence_barrier();
  }

  const int rbase = blockIdx.x * 64 + wr * 32;
  const int cbase = blockIdx.y * 64 + wc * 32;
#pragma unroll
  for (int i = 0; i < 2; ++i)
#pragma unroll
    for (int j = 0; j < 2; ++j) {
      const int col = cbase + j * 16 + l4;
      const float bv = bias ? bias[col] : 0.f;
#pragma unroll
      for (int r = 0; r < 4; ++r) {
        const int row = rbase + i * 16 + g * 4 + r;
        float v = acc[i][j][r] * alpha + bv;
        if (ACT == 1) v = fast_tanh(v);
        if (ACT == 2) v = fmaxf(v, 0.f);
        C[(size_t)row * ldc + col] = (OT)v;
      }
    }
}

// ---------------- fused score kernel ----------------
// ws[row] += sum_{c<512} tanh( (A@W^T)[row,c] ) * y[row>>4, c]
// grid 1024 blocks x 128 rows; H-chunk loop (4 x 128 cols) INSIDE the block so
// A-tiles hit L2 and the reduce/atomic epilogue runs once.
__global__ __launch_bounds__(256, 2)
void score_gemm(const bf16* __restrict__ A, const bf16* __restrict__ W,
                const bf16* __restrict__ y, int ldy, float* __restrict__ ws, int K) {
  __shared__ bf16 As[128 * 64];
  __shared__ bf16 Bs[128 * 64];
  const int tid  = threadIdx.x;
  const int wave = tid >> 6, lane = tid & 63;
  const int wr = wave >> 1, wc = wave & 1;
  const int g = lane >> 4, l4 = lane & 15;

  const bf16* Abase = A + (size_t)blockIdx.x * 128 * K;
  float p[4][4];
#pragma unroll
  for (int i = 0; i < 4; ++i)
#pragma unroll
    for (int r = 0; r < 4; ++r) p[i][r] = 0.f;

  const int rbase = blockIdx.x * 128 + wr * 64;

  for (int j = 0; j < 4; ++j) {            // H-chunk of 128 cols
    const bf16* Wj = W + (size_t)j * 128 * K;
    f32x4 acc[4][4];
#pragma unroll
    for (int i = 0; i < 4; ++i)
#pragma unroll
      for (int jj = 0; jj < 4; ++jj)
        acc[i][jj] = (f32x4){0.f, 0.f, 0.f, 0.f};

    for (int k0 = 0; k0 < K; k0 += 64) {
#pragma unroll
      for (int i = 0; i < 4; ++i) {        // 1024 chunks of 16B per tile
        const int cb  = i * 256 + wave * 64;
        const int c   = cb + lane;
        const int row = c >> 3;
        const int kk  = (c & 7) << 3;
        async16(Abase + (size_t)row * K + k0 + kk, &As[cb * 8]);
        async16(Wj    + (size_t)row * K + k0 + kk, &Bs[cb * 8]);
      }
      fence_barrier();
#pragma unroll
      for (int s = 0; s < 2; ++s) {
        const int koff = s * 32 + g * 8;
        bf16x8 af[4], bfr[4];
#pragma unroll
        for (int i = 0; i < 4; ++i)
          af[i] = *(const bf16x8*)&As[(wr * 64 + i * 16 + l4) * 64 + koff];
#pragma unroll
        for (int jj = 0; jj < 4; ++jj)
          bfr[jj] = *(const bf16x8*)&Bs[(wc * 64 + jj * 16 + l4) * 64 + koff];
#pragma unroll
        for (int i = 0; i < 4; ++i)
#pragma unroll
          for (int jj = 0; jj < 4; ++jj)
            acc[i][jj] = __builtin_amdgcn_mfma_f32_16x16x32_bf16(af[i], bfr[jj], acc[i][jj], 0, 0, 0);
      }
      fence_barrier();
    }

    // fold this chunk into per-lane score partials (rows of a 16-tile = one node)
#pragma unroll
    for (int i = 0; i < 4; ++i) {
      const int node = (rbase + i * 16) >> 4;
#pragma unroll
      for (int jj = 0; jj < 4; ++jj) {
        const float yv = (float)y[(size_t)node * ldy + j * 128 + wc * 64 + jj * 16 + l4];
        p[i][0] += fast_tanh(acc[i][jj][0]) * yv;
        p[i][1] += fast_tanh(acc[i][jj][1]) * yv;
        p[i][2] += fast_tanh(acc[i][jj][2]) * yv;
        p[i][3] += fast_tanh(acc[i][jj][3]) * yv;
      }
    }
  }

  // reduce over the 16 l4-lanes, then one atomic per row per wave (wc=0/1 combine)
#pragma unroll
  for (int i = 0; i < 4; ++i)
#pragma unroll
    for (int r = 0; r < 4; ++r) {
      float v = p[i][r];
#pragma unroll
      for (int m = 1; m < 16; m <<= 1) v += __shfl_xor(v, m);
      p[i][r] = v;
    }
  if (l4 == 0) {
#pragma unroll
    for (int i = 0; i < 4; ++i)
#pragma unroll
      for (int r = 0; r < 4; ++r)
        atomicAdd(&ws[rbase + i * 16 + g * 4 + r], p[i][r]);
  }
}

// big f32->bf16 conversions: x (1024 blocks), neibs (16384), edge (8192); 2048 elems/block
__global__ void cvt_big(const float* __restrict__ s0, bf16* __restrict__ d0,
                        const float* __restrict__ s1, bf16* __restrict__ d1,
                        const float* __restrict__ s2, bf16* __restrict__ d2) {
  const int b = blockIdx.x;
  const float* s; bf16* d; size_t base;
  if (b < 1024)       { s = s0; d = d0; base = (size_t)b * 2048; }
  else if (b < 17408) { s = s1; d = d1; base = (size_t)(b - 1024) * 2048; }
  else                { s = s2; d = d2; base = (size_t)(b - 17408) * 2048; }
  const size_t i = base + (size_t)threadIdx.x * 8;
  const float4 a = *(const float4*)(s + i);
  const float4 c = *(const float4*)(s + i + 4);
  bf16x8 o = { (bf16)a.x, (bf16)a.y, (bf16)a.z, (bf16)a.w,
               (bf16)c.x, (bf16)c.y, (bf16)c.z, (bf16)c.w };
  *(bf16x8*)(d + i) = o;
}

struct CvtEnt { const float* s; bf16* d; int n; };
struct CvtArgs { CvtEnt e[7]; };

__global__ void cvt_small(CvtArgs args) {
  const CvtEnt ent = args.e[blockIdx.y];
  const int i = blockIdx.x * 2048 + threadIdx.x * 8;
  if (i < ent.n) {
    const float4 a = *(const float4*)(ent.s + i);
    const float4 c = *(const float4*)(ent.s + i + 4);
    bf16x8 o = { (bf16)a.x, (bf16)a.y, (bf16)a.z, (bf16)a.w,
                 (bf16)c.x, (bf16)c.y, (bf16)c.z, (bf16)c.w };
    *(bf16x8*)(ent.d + i) = o;
  }
}

// fused 512x512 transpose + f32->bf16 (so y = x_att @ W2 can use the same B^T GEMM)
__global__ void transpose512f(const float* __restrict__ s, bf16* __restrict__ d) {
  __shared__ float t[16][17];
  const int x0 = blockIdx.x * 16, y0 = blockIdx.y * 16;
  t[threadIdx.y][threadIdx.x] = s[(size_t)(y0 + threadIdx.y) * 512 + x0 + threadIdx.x];
  __syncthreads();
  d[(size_t)(x0 + threadIdx.y) * 512 + (y0 + threadIdx.x)] = (bf16)t[threadIdx.x][threadIdx.y];
}

// per node: softmax over K=16 raw scores (edge scores masked), aggregate neibs/edges
__global__ void softmax_agg(const float* __restrict__ wsn, const float* __restrict__ wse,
                            const int* __restrict__ mask,
                            const bf16* __restrict__ neibs, const bf16* __restrict__ edge,
                            bf16* __restrict__ aggn, bf16* __restrict__ agge) {
  const int n = blockIdx.x;
  const int t = threadIdx.x;
  __shared__ float wn[16], we[16];
  if (t < 16) {
    wn[t] = wsn[n * 16 + t];
    we[t] = wse[n * 16 + t] - 9999999.0f * (float)mask[n * 16 + t];
  }
  __syncthreads();
  if (t == 0) {
    float m = wn[0];
    for (int k = 1; k < 16; ++k) m = fmaxf(m, wn[k]);
    float s = 0.f;
    for (int k = 0; k < 16; ++k) { wn[k] = expf(wn[k] - m); s += wn[k]; }
    s = 1.f / s;
    for (int k = 0; k < 16; ++k) wn[k] *= s;
  } else if (t == 64) {
    float m = we[0];
    for (int k = 1; k < 16; ++k) m = fmaxf(m, we[k]);
    float s = 0.f;
    for (int k = 0; k < 16; ++k) { we[k] = expf(we[k] - m); s += we[k]; }
    s = 1.f / s;
    for (int k = 0; k < 16; ++k) we[k] *= s;
  }
  __syncthreads();
  {
    const bf16* nb = neibs + (size_t)n * 16 * 256 + t;
    float a = 0.f;
#pragma unroll
    for (int k = 0; k < 16; ++k) a += wn[k] * (float)nb[(size_t)k * 256];
    aggn[(size_t)n * 256 + t] = (bf16)a;
  }
  if (t < 128) {
    const bf16* eb = edge + (size_t)n * 16 * 128 + t;
    float a = 0.f;
#pragma unroll
    for (int k = 0; k < 16; ++k) a += we[k] * (float)eb[(size_t)k * 128];
    agge[(size_t)n * 128 + t] = (bf16)a;
  }
}

extern "C" void kernel_launch(void* const* d_in, const int* in_sizes, int n_in,
                              void* d_out, int out_size, void* d_ws, size_t ws_size,
                              hipStream_t stream) {
  const float* x     = (const float*)d_in[0];
  const float* neibs = (const float*)d_in[1];
  const float* edge  = (const float*)d_in[2];
  const int*   mask  = (const int*)d_in[3];
  const float* W1x = (const float*)d_in[4];
  const float* W2x = (const float*)d_in[5];
  const float* W1n = (const float*)d_in[6];
  const float* W2n = (const float*)d_in[7];
  const float* W1e = (const float*)d_in[8];
  const float* W2e = (const float*)d_in[9];
  const float* Wfx = (const float*)d_in[10];
  const float* bfx = (const float*)d_in[11];
  const float* Wfn = (const float*)d_in[12];
  const float* bfn = (const float*)d_in[13];
  const float* Wfe = (const float*)d_in[14];
  const float* bfe = (const float*)d_in[15];
  float* out = (float*)d_out;

  char* wsb = (char*)d_ws;
  const size_t MB = 1024 * 1024;
  float* ws_n  = (float*)(wsb + 0);                // 512KB (131072 fp32)
  float* ws_e  = (float*)(wsb + 512 * 1024);       // 512KB (adjacent -> one memset)
  bf16* W2nT   = (bf16*)(wsb + 1 * MB);            // 512KB
  bf16* W2eT   = (bf16*)(wsb + 1 * MB + 512 * 1024);
  bf16* h_x    = (bf16*)(wsb + 2 * MB);            // 8MB  (reused as y_e later)
  bf16* x_att  = (bf16*)(wsb + 10 * MB);           // 8MB  (reused as aggn later)
  bf16* agge   = (bf16*)(wsb + 14 * MB);           // 2MB  (upper half of dead x_att)
  bf16* y_n    = (bf16*)(wsb + 18 * MB);           // 8MB
  bf16* xb     = (bf16*)(wsb + 26 * MB);           // 4MB
  bf16* nb     = (bf16*)(wsb + 30 * MB);           // 64MB
  bf16* eb     = (bf16*)(wsb + 94 * MB);           // 32MB
  char* wtb    = wsb + 126 * MB;                   // bf16 weights, 1.44MB
  bf16* W1xb = (bf16*)(wtb + 0);
  bf16* W2xb = (bf16*)(wtb + 256 * 1024);
  bf16* W1nb = (bf16*)(wtb + 768 * 1024);
  bf16* W1eb = (bf16*)(wtb + 1024 * 1024);
  bf16* Wfxb = (bf16*)(wtb + 1152 * 1024);
  bf16* Wfnb = (bf16*)(wtb + 1280 * 1024);
  bf16* Wfeb = (bf16*)(wtb + 1408 * 1024);
  bf16* y_e  = h_x;                                // h_x dead after x_att GEMM
  bf16* aggn = x_att;                              // x_att dead after y_e GEMM

  const float inv_sqrt512 = 0.04419417382415922f;

  hipMemsetAsync(ws_n, 0, 1 * MB, stream);  // zero ws_n + ws_e for atomics

  cvt_big<<<25600, 256, 0, stream>>>(x, xb, neibs, nb, edge, eb);

  CvtArgs ca;
  ca.e[0] = {W1x, W1xb, 131072};
  ca.e[1] = {W2x, W2xb, 262144};
  ca.e[2] = {W1n, W1nb, 131072};
  ca.e[3] = {W1e, W1eb, 65536};
  ca.e[4] = {Wfx, Wfxb, 65536};
  ca.e[5] = {Wfn, Wfnb, 65536};
  ca.e[6] = {Wfe, Wfeb, 32768};
  cvt_small<<<dim3(128, 7), 256, 0, stream>>>(ca);

  transpose512f<<<dim3(32, 32), dim3(16, 16), 0, stream>>>(W2n, W2nT);
  transpose512f<<<dim3(32, 32), dim3(16, 16), 0, stream>>>(W2e, W2eT);

  // x MLP: h_x = tanh(x @ W1x^T); x_att = h_x @ W2x^T
  gemm64<1, bf16><<<dim3(128, 8), 256, 0, stream>>>(xb, W1xb, h_x, 256, 512, 1.f, nullptr);
  gemm64<0, bf16><<<dim3(128, 8), 256, 0, stream>>>(h_x, W2xb, x_att, 512, 512, 1.f, nullptr);
  // y_n = (x_att @ W2n) / sqrt(512);  y_e = x_att @ W2e
  gemm64<0, bf16><<<dim3(128, 8), 256, 0, stream>>>(x_att, W2nT, y_n, 512, 512, inv_sqrt512, nullptr);
  gemm64<0, bf16><<<dim3(128, 8), 256, 0, stream>>>(x_att, W2eT, y_e, 512, 512, 1.f, nullptr);

  // fused scores: ws_n[r] = tanh(neibs[r] @ W1n^T) . y_n[r>>4]  (and edge analog)
  score_gemm<<<1024, 256, 0, stream>>>(nb, W1nb, y_n, 512, ws_n, 256);
  score_gemm<<<1024, 256, 0, stream>>>(eb, W1eb, y_e, 512, ws_e, 128);

  softmax_agg<<<8192, 256, 0, stream>>>(ws_n, ws_e, mask, nb, eb, aggn, agge);

  // out = relu([x@Wfx^T+bfx | aggn@Wfn^T+bfn | agge@Wfe^T+bfe]), row stride 768, f32 out
  gemm64<2, float><<<dim3(128, 4), 256, 0, stream>>>(xb,   Wfxb, out + 0,   256, 768, 1.f, bfx);
  gemm64<2, float><<<dim3(128, 4), 256, 0, stream>>>(aggn, Wfnb, out + 256, 256, 768, 1.f, bfn);
  gemm64<2, float><<<dim3(128, 4), 256, 0, stream>>>(agge, Wfeb, out + 512, 128, 768, 1.f, bfe);
}

// Round 5
// 428.760 us; speedup vs baseline: 1.2841x; 1.1212x over previous
//
#include <hip/hip_runtime.h>
#include <hip/hip_bf16.h>

typedef __bf16 bf16;
typedef __bf16 bf16x2 __attribute__((ext_vector_type(2)));
typedef __bf16 bf16x4 __attribute__((ext_vector_type(4)));
typedef __bf16 bf16x8 __attribute__((ext_vector_type(8)));
typedef float  f32x4  __attribute__((ext_vector_type(4)));

// async 16B global->LDS copy. LDS dest must be wave-uniform base; HW adds lane*16.
__device__ __forceinline__ void async16(const bf16* g, bf16* l) {
  __builtin_amdgcn_global_load_lds(
      (__attribute__((address_space(1))) void*)g,
      (__attribute__((address_space(3))) void*)l,
      16, 0, 0);
}

// Hard fence + barrier: drain ALL outstanding vmem (incl. global_load_lds LDS
// writes) and lds ops BEFORE the barrier, with a full compiler memory fence so
// no staging intrinsic can be scheduled across it (nested-loop CFG safety —
// this was the R3->R4 correctness fix; do not weaken).
__device__ __forceinline__ void fence_barrier() {
  asm volatile("s_waitcnt vmcnt(0) lgkmcnt(0)" ::: "memory");
  __syncthreads();
}

// tanh(x) = 1 - 2/(exp2(2*log2e*x)+1); v_exp_f32+v_rcp_f32, ~1e-6 abs err
__device__ __forceinline__ float fast_tanh(float x) {
  float e = __builtin_amdgcn_exp2f(x * 2.88539008177793f);
  return 1.f - 2.f * __builtin_amdgcn_rcpf(e + 1.f);
}

// ---------------- 64x64-tile GEMM: C = act(alpha*(A@W^T)+bias) ----------------
// A:[M,K] bf16 rm, W:[N,K] bf16 rm. 256 thr = 4 waves, each 32x32 via 2x2 MFMA.
// ACT: 0 none, 1 tanh, 2 relu.  OT: bf16 or float.
template<int ACT, typename OT>
__global__ __launch_bounds__(256, 4)
void gemm64(const bf16* __restrict__ A, const bf16* __restrict__ W,
            OT* __restrict__ C, int K, int ldc, float alpha,
            const float* __restrict__ bias) {
  __shared__ bf16 As[64 * 64];
  __shared__ bf16 Bs[64 * 64];
  const int tid  = threadIdx.x;
  const int wave = tid >> 6, lane = tid & 63;
  const int wr = wave >> 1, wc = wave & 1;
  const int g = lane >> 4, l4 = lane & 15;

  f32x4 acc[2][2];
#pragma unroll
  for (int i = 0; i < 2; ++i)
#pragma unroll
    for (int j = 0; j < 2; ++j)
      acc[i][j] = (f32x4){0.f, 0.f, 0.f, 0.f};

  const bf16* Abase = A + (size_t)blockIdx.x * 64 * K;
  const bf16* Wbase = W + (size_t)blockIdx.y * 64 * K;

  for (int k0 = 0; k0 < K; k0 += 64) {
#pragma unroll
    for (int i = 0; i < 2; ++i) {          // 512 chunks of 16B per tile
      const int cb  = i * 256 + wave * 64; // wave-uniform
      const int c   = cb + lane;
      const int row = c >> 3;
      const int kk  = (c & 7) << 3;
      async16(Abase + (size_t)row * K + k0 + kk, &As[cb * 8]);
      async16(Wbase + (size_t)row * K + k0 + kk, &Bs[cb * 8]);
    }
    fence_barrier();
#pragma unroll
    for (int s = 0; s < 2; ++s) {
      const int koff = s * 32 + g * 8;
      bf16x8 af[2], bfr[2];
#pragma unroll
      for (int i = 0; i < 2; ++i)
        af[i] = *(const bf16x8*)&As[(wr * 32 + i * 16 + l4) * 64 + koff];
#pragma unroll
      for (int j = 0; j < 2; ++j)
        bfr[j] = *(const bf16x8*)&Bs[(wc * 32 + j * 16 + l4) * 64 + koff];
#pragma unroll
      for (int i = 0; i < 2; ++i)
#pragma unroll
        for (int j = 0; j < 2; ++j)
          acc[i][j] = __builtin_amdgcn_mfma_f32_16x16x32_bf16(af[i], bfr[j], acc[i][j], 0, 0, 0);
    }
    fence_barrier();
  }

  const int rbase = blockIdx.x * 64 + wr * 32;
  const int cbase = blockIdx.y * 64 + wc * 32;
#pragma unroll
  for (int i = 0; i < 2; ++i)
#pragma unroll
    for (int j = 0; j < 2; ++j) {
      const int col = cbase + j * 16 + l4;
      const float bv = bias ? bias[col] : 0.f;
#pragma unroll
      for (int r = 0; r < 4; ++r) {
        const int row = rbase + i * 16 + g * 4 + r;
        float v = acc[i][j][r] * alpha + bv;
        if (ACT == 1) v = fast_tanh(v);
        if (ACT == 2) v = fmaxf(v, 0.f);
        C[(size_t)row * ldc + col] = (OT)v;
      }
    }
}

// ---------------- fused score + softmax + aggregate ----------------
// Per block: 64 A-rows = 4 nodes.  s[row] = scale * sum_{c<512} tanh((A@W^T)[row,c]) * y[node,c]
// then per-node masked softmax over the 16 rows, then agg[node,:] = sum_k w[k]*A[node*16+k,:].
// A is f32 (converted to bf16 once into a persistent LDS tile, also reused for agg).
// Waves: 4, wave w owns cols w*64 of a 256-col H-chunk (j-loop of 2). 16 MFMA : 8 ds_read_b128.
template<int D>
__global__ __launch_bounds__(256, 2)
void score_agg(const float* __restrict__ A, const bf16* __restrict__ Wb,
               const bf16* __restrict__ y, int ldy, int yoff, float scale,
               const int* __restrict__ mask, bf16* __restrict__ agg) {
  __shared__ bf16 As[64 * D];     // persistent block A-tile (bf16)
  __shared__ bf16 Bs[256 * 64];   // W chunk tile; overlaid by sred/wgt after main loop
  float* sred = (float*)Bs;       // [4][64] per-wave row partials
  float* wgt  = (float*)Bs + 256; // [64] softmax weights
  const int tid  = threadIdx.x;
  const int wave = tid >> 6, lane = tid & 63;
  const int g = lane >> 4, l4 = lane & 15;
  const int blk = blockIdx.x;

  // ---- stage full 64xD A block: f32 global -> bf16 LDS (coalesced float4) ----
  const float* Ab = A + (size_t)blk * 64 * D;
  constexpr int F4PR = D / 4;
#pragma unroll
  for (int ii = 0; ii < D / 16; ++ii) {
    const int c    = ii * 256 + tid;
    const int row  = c / F4PR;
    const int col4 = (c % F4PR) * 4;
    const float4 v = *(const float4*)(Ab + (size_t)row * D + col4);
    bf16x4 o = {(bf16)v.x, (bf16)v.y, (bf16)v.z, (bf16)v.w};
    *(bf16x4*)&As[row * D + col4] = o;
  }

  float p[4][4];
#pragma unroll
  for (int i = 0; i < 4; ++i)
#pragma unroll
    for (int r = 0; r < 4; ++r) p[i][r] = 0.f;

  fence_barrier();

  for (int j = 0; j < 2; ++j) {            // H-chunk of 256 cols
    const bf16* Wj = Wb + (size_t)j * 256 * D;
    f32x4 acc[4][4];
#pragma unroll
    for (int i = 0; i < 4; ++i)
#pragma unroll
      for (int jj = 0; jj < 4; ++jj)
        acc[i][jj] = (f32x4){0.f, 0.f, 0.f, 0.f};

    for (int k0 = 0; k0 < D; k0 += 64) {
#pragma unroll
      for (int i = 0; i < 8; ++i) {        // 2048 chunks of 16B (256x64 tile)
        const int cb  = i * 256 + wave * 64;
        const int c   = cb + lane;
        const int row = c >> 3;
        const int kk  = (c & 7) << 3;
        async16(Wj + (size_t)row * D + k0 + kk, &Bs[cb * 8]);
      }
      fence_barrier();
#pragma unroll
      for (int s = 0; s < 2; ++s) {
        const int koff = s * 32 + g * 8;
        bf16x8 af[4], bfr[4];
#pragma unroll
        for (int i = 0; i < 4; ++i)
          af[i] = *(const bf16x8*)&As[(i * 16 + l4) * D + k0 + koff];
#pragma unroll
        for (int jj = 0; jj < 4; ++jj)
          bfr[jj] = *(const bf16x8*)&Bs[(wave * 64 + jj * 16 + l4) * 64 + koff];
#pragma unroll
        for (int i = 0; i < 4; ++i)
#pragma unroll
          for (int jj = 0; jj < 4; ++jj)
            acc[i][jj] = __builtin_amdgcn_mfma_f32_16x16x32_bf16(af[i], bfr[jj], acc[i][jj], 0, 0, 0);
      }
      fence_barrier();
    }

    // fold chunk into per-lane score partials (rows i*16.. all belong to node i)
#pragma unroll
    for (int i = 0; i < 4; ++i) {
      const size_t yb = (size_t)(blk * 4 + i) * ldy + yoff + j * 256 + wave * 64;
#pragma unroll
      for (int jj = 0; jj < 4; ++jj) {
        const float yv = (float)y[yb + jj * 16 + l4];
        p[i][0] += fast_tanh(acc[i][jj][0]) * yv;
        p[i][1] += fast_tanh(acc[i][jj][1]) * yv;
        p[i][2] += fast_tanh(acc[i][jj][2]) * yv;
        p[i][3] += fast_tanh(acc[i][jj][3]) * yv;
      }
    }
  }

  // reduce over the 16 l4-lanes; lane l4==0 of each g-group holds the wave partial
#pragma unroll
  for (int i = 0; i < 4; ++i)
#pragma unroll
    for (int r = 0; r < 4; ++r) {
      float v = p[i][r];
#pragma unroll
      for (int m = 1; m < 16; m <<= 1) v += __shfl_xor(v, m);
      p[i][r] = v;
    }
  // all waves are past the final fence_barrier -> Bs region is dead; overlay sred
  if (l4 == 0) {
#pragma unroll
    for (int i = 0; i < 4; ++i)
#pragma unroll
      for (int r = 0; r < 4; ++r)
        sred[wave * 64 + i * 16 + g * 4 + r] = p[i][r];
  }
  __syncthreads();

  // ---- per-node masked softmax over 16 rows (threads 0..63 = wave 0) ----
  if (tid < 64) {
    const int node_g = blk * 4 + (tid >> 4);
    float s = (sred[tid] + sred[64 + tid] + sred[128 + tid] + sred[192 + tid]) * scale;
    if (mask) s -= 9999999.0f * (float)mask[node_g * 16 + (tid & 15)];
    float m = s;
#pragma unroll
    for (int d = 1; d < 16; d <<= 1) m = fmaxf(m, __shfl_xor(m, d));
    float e = __builtin_amdgcn_exp2f((s - m) * 1.44269504088896f);
    float sum = e;
#pragma unroll
    for (int d = 1; d < 16; d <<= 1) sum += __shfl_xor(sum, d);
    wgt[tid] = e / sum;
  }
  __syncthreads();

  // ---- aggregate from the LDS A-tile: agg[node,d] = sum_k wgt[k]*As[node*16+k, d] ----
  constexpr int EPT = D / 64;              // elems per thread (4 for D=256, 2 for D=128)
  const int n  = tid >> 6;                 // local node
  const int dl = (tid & 63) * EPT;
  float a[EPT];
#pragma unroll
  for (int e = 0; e < EPT; ++e) a[e] = 0.f;
#pragma unroll
  for (int k = 0; k < 16; ++k) {
    const float w = wgt[n * 16 + k];
    if constexpr (EPT == 4) {
      bf16x4 v = *(const bf16x4*)&As[(n * 16 + k) * D + dl];
      a[0] += w * (float)v[0]; a[1] += w * (float)v[1];
      a[2] += w * (float)v[2]; a[3] += w * (float)v[3];
    } else {
      bf16x2 v = *(const bf16x2*)&As[(n * 16 + k) * D + dl];
      a[0] += w * (float)v[0]; a[1] += w * (float)v[1];
    }
  }
  if constexpr (EPT == 4) {
    bf16x4 o = {(bf16)a[0], (bf16)a[1], (bf16)a[2], (bf16)a[3]};
    *(bf16x4*)&agg[(size_t)(blk * 4 + n) * D + dl] = o;
  } else {
    bf16x2 o = {(bf16)a[0], (bf16)a[1]};
    *(bf16x2*)&agg[(size_t)(blk * 4 + n) * D + dl] = o;
  }
}

// batched f32->bf16 conversion (x + 7 weight matrices); all sizes % 2048 == 0
struct CvtEnt { const float* s; bf16* d; int n; };
struct CvtArgs { CvtEnt e[8]; };

__global__ void cvt_small(CvtArgs args) {
  const CvtEnt ent = args.e[blockIdx.y];
  const int i = blockIdx.x * 2048 + threadIdx.x * 8;
  if (i < ent.n) {
    const float4 a = *(const float4*)(ent.s + i);
    const float4 c = *(const float4*)(ent.s + i + 4);
    bf16x8 o = { (bf16)a.x, (bf16)a.y, (bf16)a.z, (bf16)a.w,
                 (bf16)c.x, (bf16)c.y, (bf16)c.z, (bf16)c.w };
    *(bf16x8*)(ent.d + i) = o;
  }
}

// fused 512x512 transpose + f32->bf16 for both W2 matrices (z selects)
__global__ void transpose2(const float* __restrict__ s0, bf16* __restrict__ d0,
                           const float* __restrict__ s1, bf16* __restrict__ d1) {
  __shared__ float t[16][17];
  const float* s = blockIdx.z ? s1 : s0;
  bf16* d = blockIdx.z ? d1 : d0;
  const int x0 = blockIdx.x * 16, y0 = blockIdx.y * 16;
  t[threadIdx.y][threadIdx.x] = s[(size_t)(y0 + threadIdx.y) * 512 + x0 + threadIdx.x];
  __syncthreads();
  d[(size_t)(x0 + threadIdx.y) * 512 + (y0 + threadIdx.x)] = (bf16)t[threadIdx.x][threadIdx.y];
}

extern "C" void kernel_launch(void* const* d_in, const int* in_sizes, int n_in,
                              void* d_out, int out_size, void* d_ws, size_t ws_size,
                              hipStream_t stream) {
  const float* x     = (const float*)d_in[0];
  const float* neibs = (const float*)d_in[1];
  const float* edge  = (const float*)d_in[2];
  const int*   mask  = (const int*)d_in[3];
  const float* W1x = (const float*)d_in[4];
  const float* W2x = (const float*)d_in[5];
  const float* W1n = (const float*)d_in[6];
  const float* W2n = (const float*)d_in[7];
  const float* W1e = (const float*)d_in[8];
  const float* W2e = (const float*)d_in[9];
  const float* Wfx = (const float*)d_in[10];
  const float* bfx = (const float*)d_in[11];
  const float* Wfn = (const float*)d_in[12];
  const float* bfn = (const float*)d_in[13];
  const float* Wfe = (const float*)d_in[14];
  const float* bfe = (const float*)d_in[15];
  float* out = (float*)d_out;

  char* wsb = (char*)d_ws;
  const size_t MB = 1024 * 1024;
  bf16* W2nT = (bf16*)(wsb + 0);             // 512KB  (Wcat = [W2nT; W2eT] contiguous)
  bf16* W2eT = (bf16*)(wsb + 512 * 1024);    // 512KB
  char* wtb  = wsb + 1 * MB;                 // bf16 weights
  bf16* W1xb = (bf16*)(wtb + 0);             // 256KB
  bf16* W2xb = (bf16*)(wtb + 256 * 1024);    // 512KB
  bf16* W1nb = (bf16*)(wtb + 768 * 1024);    // 256KB
  bf16* W1eb = (bf16*)(wtb + 1024 * 1024);   // 128KB
  bf16* Wfxb = (bf16*)(wtb + 1152 * 1024);   // 128KB
  bf16* Wfnb = (bf16*)(wtb + 1280 * 1024);   // 128KB
  bf16* Wfeb = (bf16*)(wtb + 1408 * 1024);   // 64KB
  bf16* xb    = (bf16*)(wsb + 3 * MB);       // 4MB
  bf16* h_x   = (bf16*)(wsb + 7 * MB);       // 8MB
  bf16* x_att = (bf16*)(wsb + 15 * MB);      // 8MB
  bf16* ycat  = (bf16*)(wsb + 23 * MB);      // 16MB  [8192,1024] = [y_n | y_e]
  bf16* aggn  = (bf16*)(wsb + 39 * MB);      // 4MB
  bf16* agge  = (bf16*)(wsb + 43 * MB);      // 2MB

  const float inv_sqrt512 = 0.04419417382415922f;

  CvtArgs ca;
  ca.e[0] = {x,   xb,   2097152};
  ca.e[1] = {W1x, W1xb, 131072};
  ca.e[2] = {W2x, W2xb, 262144};
  ca.e[3] = {W1n, W1nb, 131072};
  ca.e[4] = {W1e, W1eb, 65536};
  ca.e[5] = {Wfx, Wfxb, 65536};
  ca.e[6] = {Wfn, Wfnb, 65536};
  ca.e[7] = {Wfe, Wfeb, 32768};
  cvt_small<<<dim3(1024, 8), 256, 0, stream>>>(ca);

  transpose2<<<dim3(32, 32, 2), dim3(16, 16), 0, stream>>>(W2n, W2nT, W2e, W2eT);

  // x MLP: h_x = tanh(x @ W1x^T); x_att = h_x @ W2x^T
  gemm64<1, bf16><<<dim3(128, 8), 256, 0, stream>>>(xb, W1xb, h_x, 256, 512, 1.f, nullptr);
  gemm64<0, bf16><<<dim3(128, 8), 256, 0, stream>>>(h_x, W2xb, x_att, 512, 512, 1.f, nullptr);
  // ycat = x_att @ [W2n | W2e]  (cols 0..511 = y_n unscaled, 512..1023 = y_e)
  gemm64<0, bf16><<<dim3(128, 16), 256, 0, stream>>>(x_att, W2nT, ycat, 512, 1024, 1.f, nullptr);

  // fused score+softmax+aggregate (neib scaled by 1/sqrt(512); edge masked)
  score_agg<256><<<2048, 256, 0, stream>>>(neibs, W1nb, ycat, 1024, 0, inv_sqrt512, nullptr, aggn);
  score_agg<128><<<2048, 256, 0, stream>>>(edge,  W1eb, ycat, 1024, 512, 1.f, mask, agge);

  // out = relu([x@Wfx^T+bfx | aggn@Wfn^T+bfn | agge@Wfe^T+bfe]), row stride 768, f32 out
  gemm64<2, float><<<dim3(128, 4), 256, 0, stream>>>(xb,   Wfxb, out + 0,   256, 768, 1.f, bfx);
  gemm64<2, float><<<dim3(128, 4), 256, 0, stream>>>(aggn, Wfnb, out + 256, 256, 768, 1.f, bfn);
  gemm64<2, float><<<dim3(128, 4), 256, 0, stream>>>(agge, Wfeb, out + 512, 128, 768, 1.f, bfe);
}